// Round 5
// baseline (369.589 us; speedup 1.0000x reference)
//
#include <hip/hip_runtime.h>

using f32x4  = __attribute__((ext_vector_type(4))) float;
using bf16x8 = __attribute__((ext_vector_type(8))) short;

#define SEQ 1025
#define NH  12

__device__ __forceinline__ unsigned short f2bf(float f) {
  unsigned u = __float_as_uint(f);
  u += 0x7FFFu + ((u >> 16) & 1u);        // RNE; inputs are finite
  return (unsigned short)(u >> 16);
}

// cheap round-to-nearest (ties up) for P values (p >= 0, feeds PV MFMA)
__device__ __forceinline__ unsigned short f2bf_p(float f) {
  return (unsigned short)((__float_as_uint(f) + 0x8000u) >> 16);
}

__device__ __forceinline__ void async16(const void* g, void* s) {
  __builtin_amdgcn_global_load_lds(
      (const __attribute__((address_space(1))) void*)g,
      (__attribute__((address_space(3))) void*)s, 16, 0, 0);
}

// ---------------- X fp32 -> bf16, padded to 8320 rows (zeros) ----------------
__global__ __launch_bounds__(256) void conv_x(const float* __restrict__ X,
                                              ushort* __restrict__ Xb) {
  int t = blockIdx.x * 256 + threadIdx.x;
  if (t >= 8320 * 96) return;
  int row = t / 96;
  size_t e = (size_t)t * 8;
  union { uint4 q; ushort us[8]; } o;
  if (row < 8200) {
    float4 f0 = *(const float4*)(X + e);
    float4 f1 = *(const float4*)(X + e + 4);
    o.us[0] = f2bf(f0.x); o.us[1] = f2bf(f0.y); o.us[2] = f2bf(f0.z); o.us[3] = f2bf(f0.w);
    o.us[4] = f2bf(f1.x); o.us[5] = f2bf(f1.y); o.us[6] = f2bf(f1.z); o.us[7] = f2bf(f1.w);
  } else {
    o.q = make_uint4(0, 0, 0, 0);
  }
  *(uint4*)(Xb + e) = o.q;
}

// ---------------- W[q|k|v] [K=768][N=768] fp32 -> Wt [N=2304][K=768] bf16 ----
__global__ __launch_bounds__(256) void pack_w(const float* __restrict__ Wq,
                                              const float* __restrict__ Wk,
                                              const float* __restrict__ Wv,
                                              ushort* __restrict__ Wt) {
  __shared__ float tile[32][33];
  const int nt = blockIdx.x;
  const int kt = blockIdx.y;
  const int sel = nt / 24;
  const int o0 = (nt - sel * 24) * 32;
  const int k0 = kt * 32;
  const float* W = sel == 0 ? Wq : sel == 1 ? Wk : Wv;
  const int t = threadIdx.x;
  const int x = t & 31, y = t >> 5;
  for (int p = 0; p < 4; ++p)
    tile[y + p * 8][x] = W[(size_t)(k0 + y + p * 8) * 768 + o0 + x];
  __syncthreads();
  for (int p = 0; p < 4; ++p) {
    const int nl = y + p * 8;
    Wt[(size_t)(nt * 32 + nl) * 768 + k0 + x] = f2bf(tile[x][nl]);
  }
}

__global__ __launch_bounds__(256) void pack_bias(const float* __restrict__ bq,
                                                 const float* __restrict__ bk,
                                                 const float* __restrict__ bv,
                                                 float* __restrict__ bc) {
  int t = blockIdx.x * 256 + threadIdx.x;
  if (t < 768) bc[t] = bq[t];
  else if (t < 1536) bc[t] = bk[t - 768];
  else if (t < 2304) bc[t] = bv[t - 1536];
}

// ---------------- rel_bias repack: [H][S][S] -> MFMA C-frag order -----------
// biasF[h][kt=17][w16=72][lane=64][e=16], e = ct*4+r2; value pre-scaled by
// log2(e), cols>1024 pre-masked to -3e30, rows>1024 clamped (never stored).
// In attn, a wave's per-(rt,kt) bias becomes ONE contiguous 64 B chunk/lane.
__global__ __launch_bounds__(256, 2) void repack_bias_frag(
    const float* __restrict__ rel, float* __restrict__ bf) {
  __shared__ float lds[16][1092];               // stride 1092: banks offset by 4/row
  const int h = blockIdx.x / 72;
  const int w = blockIdx.x - h * 72;
  const int t = threadIdx.x;
  const float* src = rel + (size_t)h * SEQ * SEQ;
  for (int r = 0; r < 16; ++r) {
    int q = w * 16 + r; if (q > 1024) q = 1024;
    const float* row = src + (size_t)q * SEQ;
    for (int c = t; c < 1088; c += 256)
      lds[r][c] = (c <= 1024) ? row[c] * 1.44269504f : -3.0e30f;
  }
  __syncthreads();
  float* dst = bf + ((size_t)h * 17 * 72 + w) * 1024;
  for (int kt = 0; kt < 17; ++kt) {
    float* d = dst + (size_t)kt * (72 * 1024);
    for (int j = t; j < 1024; j += 256) {
      int lane = j >> 4, e = j & 15;
      int ct = e >> 2, r2 = e & 3;
      int row = ((lane >> 4) << 2) + r2;
      int col = kt * 64 + ct * 16 + (lane & 15);
      d[j] = lds[row][col];
    }
  }
}

// ---------------- fused QKV GEMM: [8320x768]*[768x2304] -> Q/K/V [B,H,S,64] --
__global__ __launch_bounds__(256) void gemm_qkv(const ushort* __restrict__ A,
                                                const ushort* __restrict__ Bt,
                                                const float* __restrict__ bias,
                                                ushort* __restrict__ Qo,
                                                ushort* __restrict__ Ko,
                                                ushort* __restrict__ Vo) {
  __shared__ ushort a_sm[128 * 32];
  __shared__ ushort b_sm[128 * 32];
  const int t = threadIdx.x;
  const int lane = t & 63, wave = t >> 6;
  const int quad = lane >> 4, l16 = lane & 15;
  const int wrow = wave >> 1, wcol = wave & 1;
  const int m0 = blockIdx.x * 128, n0 = blockIdx.y * 128;

  f32x4 acc[4][4] = {};

  const ushort* a_g = A + (size_t)m0 * 768;
  const ushort* b_g = Bt + (size_t)n0 * 768;

  for (int k0 = 0; k0 < 768; k0 += 32) {
    __syncthreads();
    for (int r = 0; r < 2; ++r) {
      int c = r * 256 + t;
      int row = c >> 2;
      int colb = (c & 3) * 16;
      async16((const char*)(a_g + (size_t)row * 768 + k0) + colb, (char*)a_sm + c * 16);
      async16((const char*)(b_g + (size_t)row * 768 + k0) + colb, (char*)b_sm + c * 16);
    }
    __syncthreads();
    bf16x8 af[4], bfr[4];
    for (int i = 0; i < 4; ++i) {
      af[i]  = *(const bf16x8*)(a_sm + (wrow * 64 + i * 16 + l16) * 32 + quad * 8);
      bfr[i] = *(const bf16x8*)(b_sm + (wcol * 64 + i * 16 + l16) * 32 + quad * 8);
    }
    for (int i = 0; i < 4; ++i)
      for (int j = 0; j < 4; ++j)
        acc[i][j] = __builtin_amdgcn_mfma_f32_16x16x32_bf16(af[i], bfr[j], acc[i][j], 0, 0, 0);
  }

  for (int j = 0; j < 4; ++j) {
    const int gn = n0 + wcol * 64 + j * 16 + l16;
    const int sel = gn / 768;
    const int o = gn - sel * 768;
    const int hh = o >> 6, hd = o & 63;
    const float bv = bias[gn];
    ushort* dst = sel == 0 ? Qo : sel == 1 ? Ko : Vo;
    for (int i = 0; i < 4; ++i) {
      const int gmb = m0 + wrow * 64 + i * 16 + quad * 4;
      for (int r = 0; r < 4; ++r) {
        const int gm = gmb + r;
        if (gm < 8200) {
          const int bb = gm / 1025;
          const int ss = gm - bb * 1025;
          dst[(((size_t)(bb * NH + hh) * SEQ + ss) << 6) + hd] = f2bf(acc[i][j][r] + bv);
        }
      }
    }
  }
}

// ---------------- flash attention v5 ----------------------------------------
// block = 4 waves, one (b,h), 128 q-rows, k-tile 64, 17 iters.
// Bias in C-frag order: 8 dwordx4/lane/iter, wave-contiguous (was 32 scattered
// dwords x 4 segments -> the L1 transaction storm). K/V register-prefetched.
// Swizzle: XCD = id&7; all 9 qt-blocks of one (b,h) on one XCD (K/V 1 L2 copy).
// LDS: p 4x[32][72] = 18432 | K [64][72] = 9216 | V^T [64][72] = 9216 -> 36864.
__global__ __launch_bounds__(256, 4) void attn(const ushort* __restrict__ Qb,
                                               const ushort* __restrict__ Kb,
                                               const ushort* __restrict__ Vb,
                                               const float* __restrict__ biasF,
                                               float* __restrict__ out) {
  __shared__ char smem[36864];
  ushort* p_sm = (ushort*)smem;                 // 4 x [32][72]
  ushort* k_sm = (ushort*)(smem + 18432);       // [64][72]
  ushort* v_sm = (ushort*)(smem + 27648);       // [64][72] transposed [hd][k]

  const int t = threadIdx.x;
  const int lane = t & 63, wave = t >> 6;
  const int quad = lane >> 4, l16 = lane & 15;

  // swizzle: XCD x = id&7; group G = Gg*8+x covers (b,h); all 9 qt of a
  // group share that XCD -> K/V fetched into one L2.
  const int id = blockIdx.x;                    // [0,864)
  const int x = id & 7, s = id >> 3;            // s in [0,108)
  const int Gg = s / 9, qt = s - Gg * 9;
  const int G = Gg * 8 + x;                     // [0,96)
  const int b = G / 12, h = G - b * 12;
  const int q0 = qt * 128;

  const size_t bh = (size_t)(b * NH + h) * SEQ * 64;
  const ushort* Qp = Qb + bh;
  const ushort* Kp = Kb + bh;
  const ushort* Vp = Vb + bh;

  // ---- prefetch state ----
  uint4 kpre0, kpre1, vpre0, vpre1;
  const int vkp2 = t & 31, vhb = (t >> 5) * 8;

  auto issue_kv = [&](int kb) {
    {
      int c = t, row = c >> 3, cb = (c & 7) * 8;
      int rk = kb + row; if (rk > 1024) rk = 1024;
      kpre0 = *(const uint4*)(Kp + (size_t)rk * 64 + cb);
    }
    {
      int c = t + 256, row = c >> 3, cb = (c & 7) * 8;
      int rk = kb + row; if (rk > 1024) rk = 1024;
      kpre1 = *(const uint4*)(Kp + (size_t)rk * 64 + cb);
    }
    {
      int r0 = kb + vkp2 * 2;
      int r0c = r0 > 1024 ? 1024 : r0;
      int r1c = r0 + 1 > 1024 ? 1024 : r0 + 1;
      vpre0 = *(const uint4*)(Vp + (size_t)r0c * 64 + vhb);
      vpre1 = *(const uint4*)(Vp + (size_t)r1c * 64 + vhb);
    }
  };

  issue_kv(0);

  // ---- stage this wave's 32 Q rows into its own p region, grab frags ----
  ushort* pw = p_sm + wave * (32 * 72);
  const int qbase = q0 + wave * 32;
  for (int i = 0; i < 4; ++i) {
    int c = lane + 64 * i;
    int row = c >> 3, cb = (c & 7) * 8;
    int rq = qbase + row; if (rq > 1024) rq = 1024;   // OOB rows: junk, never stored
    *(uint4*)(pw + row * 72 + cb) = *(const uint4*)(Qp + (size_t)rq * 64 + cb);
  }
  bf16x8 qf[2][2];
  for (int rt = 0; rt < 2; ++rt)
    for (int ks = 0; ks < 2; ++ks)
      qf[rt][ks] = *(const bf16x8*)(pw + (rt * 16 + l16) * 72 + ks * 32 + quad * 8);

  float lst[8] = {0, 0, 0, 0, 0, 0, 0, 0};
  f32x4 oacc[2][4] = {};
  const float c_scale = 0.18033688f;            // (1/8) * log2(e)
  // frag-order bias: wave's rt=0 window w = qt*8+wave*2, rt=1 at +1
  const float* bf_base = biasF +
      ((size_t)h * 17 * 72 + (qt * 8 + wave * 2)) * 1024 + (lane << 4);

  for (int kt = 0; kt < 17; ++kt) {
    __syncthreads();                            // prior tile's readers done
    // ---- store prefetched K/V to LDS ----
    {
      int c = t;
      *(uint4*)(k_sm + (c >> 3) * 72 + (c & 7) * 8) = kpre0;
      c = t + 256;
      *(uint4*)(k_sm + (c >> 3) * 72 + (c & 7) * 8) = kpre1;
    }
    {
      union { uint4 q; ushort us[8]; } e0, e1;
      e0.q = vpre0; e1.q = vpre1;
      for (int e = 0; e < 8; ++e)
        *(unsigned*)(v_sm + (vhb + e) * 72 + vkp2 * 2) =
            (unsigned)e0.us[e] | ((unsigned)e1.us[e] << 16);
    }
    __syncthreads();                            // tile visible to all waves

    // ---- bias: 8 contiguous dwordx4 per lane (C-frag order) ----
    const float* bfp = bf_base + (size_t)kt * (72 * 1024);
    f32x4 br[2][4];
    for (int rt = 0; rt < 2; ++rt)
      for (int ct = 0; ct < 4; ++ct)
        br[rt][ct] = *(const f32x4*)(bfp + rt * 1024 + ct * 4);

    if (kt < 16) issue_kv(kt * 64 + 64);        // in flight across compute

    // ---- Sc = Q K^T : 32 q-rows x 64 keys per wave ----
    f32x4 sc[2][4] = {};
    for (int ct = 0; ct < 4; ++ct)
      for (int ks = 0; ks < 2; ++ks) {
        bf16x8 kf = *(const bf16x8*)(k_sm + (ct * 16 + l16) * 72 + ks * 32 + quad * 8);
        sc[0][ct] = __builtin_amdgcn_mfma_f32_16x16x32_bf16(qf[0][ks], kf, sc[0][ct], 0, 0, 0);
        sc[1][ct] = __builtin_amdgcn_mfma_f32_16x16x32_bf16(qf[1][ks], kf, sc[1][ct], 0, 0, 0);
      }

    // ---- p = exp2(sc*scale + bias); accumulate l; write P ----
    for (int rt = 0; rt < 2; ++rt)
      for (int ct = 0; ct < 4; ++ct)
        for (int r2 = 0; r2 < 4; ++r2) {
          float p = __builtin_amdgcn_exp2f(
              fmaf(sc[rt][ct][r2], c_scale, br[rt][ct][r2]));
          lst[rt * 4 + r2] += p;
          pw[(rt * 16 + quad * 4 + r2) * 72 + ct * 16 + l16] = f2bf_p(p);
        }

    // ---- PV ----
    for (int ks = 0; ks < 2; ++ks) {
      bf16x8 pf0 = *(const bf16x8*)(pw + l16 * 72 + ks * 32 + quad * 8);
      bf16x8 pf1 = *(const bf16x8*)(pw + (16 + l16) * 72 + ks * 32 + quad * 8);
      for (int c4 = 0; c4 < 4; ++c4) {
        bf16x8 vf = *(const bf16x8*)(v_sm + (c4 * 16 + l16) * 72 + ks * 32 + quad * 8);
        oacc[0][c4] = __builtin_amdgcn_mfma_f32_16x16x32_bf16(pf0, vf, oacc[0][c4], 0, 0, 0);
        oacc[1][c4] = __builtin_amdgcn_mfma_f32_16x16x32_bf16(pf1, vf, oacc[1][c4], 0, 0, 0);
      }
    }
  }

  // ---- epilogue: reduce l across the 16-lane key groups, normalize, store ----
  for (int si = 0; si < 8; ++si) {
    float s2 = lst[si];
    s2 += __shfl_xor(s2, 1);
    s2 += __shfl_xor(s2, 2);
    s2 += __shfl_xor(s2, 4);
    s2 += __shfl_xor(s2, 8);
    lst[si] = s2;
  }
  for (int rt = 0; rt < 2; ++rt)
    for (int r2 = 0; r2 < 4; ++r2) {
      int sr = qbase + rt * 16 + quad * 4 + r2;
      if (sr < SEQ) {
        float inv = 1.0f / lst[rt * 4 + r2];
        float* op = out + ((size_t)b * SEQ + sr) * 768 + h * 64;
        for (int c4 = 0; c4 < 4; ++c4)
          op[c4 * 16 + l16] = oacc[rt][c4][r2] * inv;
      }
    }
}

// ---------------- launch ----------------
extern "C" void kernel_launch(void* const* d_in, const int* in_sizes, int n_in,
                              void* d_out, int out_size, void* d_ws, size_t ws_size,
                              hipStream_t stream) {
  const float* X  = (const float*)d_in[0];
  const float* rb = (const float*)d_in[1];
  const float* Wq = (const float*)d_in[2];
  const float* bq = (const float*)d_in[3];
  const float* Wk = (const float*)d_in[4];
  const float* bk = (const float*)d_in[5];
  const float* Wv = (const float*)d_in[6];
  const float* bv = (const float*)d_in[7];
  float* out = (float*)d_out;
  char* ws = (char*)d_ws;

  // layout (biasF overlays Xb/Wt/biasc, which are dead after gemm_qkv):
  ushort* Qb    = (ushort*)ws;                          // 12,595,200 B
  ushort* Kb    = (ushort*)(ws + 12595200);
  ushort* Vb    = (ushort*)(ws + 25190400);             // ends 37,785,600
  ushort* Xb    = (ushort*)(ws + 37785600);             // 12,779,520 -> 50,565,120
  ushort* Wt    = (ushort*)(ws + 50565120);             //  3,538,944 -> 54,104,064
  float*  biasc = (float*)(ws + 54104064);              //      9,216 -> 54,113,280
  float*  biasF = (float*)(ws + 37785600);              // 60,162,048 -> 97,947,648

  conv_x<<<3120, 256, 0, stream>>>(X, Xb);
  pack_w<<<dim3(72, 24), 256, 0, stream>>>(Wq, Wk, Wv, Wt);
  pack_bias<<<9, 256, 0, stream>>>(bq, bk, bv, biasc);
  gemm_qkv<<<dim3(65, 18), 256, 0, stream>>>(Xb, Wt, biasc, Qb, Kb, Vb);
  repack_bias_frag<<<NH * 72, 256, 0, stream>>>(rb, biasF);
  attn<<<864, 256, 0, stream>>>(Qb, Kb, Vb, biasF, out);
}

// Round 6
// 317.814 us; speedup vs baseline: 1.1629x; 1.1629x over previous
//
#include <hip/hip_runtime.h>

using f32x4  = __attribute__((ext_vector_type(4))) float;
using bf16x8 = __attribute__((ext_vector_type(8))) short;

#define SEQ 1025
#define NH  12

__device__ __forceinline__ unsigned short f2bf(float f) {
  unsigned u = __float_as_uint(f);
  u += 0x7FFFu + ((u >> 16) & 1u);        // RNE; inputs are finite
  return (unsigned short)(u >> 16);
}

// cheap round-to-nearest (ties up) for P values (p >= 0, feeds PV MFMA)
__device__ __forceinline__ unsigned short f2bf_p(float f) {
  return (unsigned short)((__float_as_uint(f) + 0x8000u) >> 16);
}

__device__ __forceinline__ void async16(const void* g, void* s) {
  __builtin_amdgcn_global_load_lds(
      (const __attribute__((address_space(1))) void*)g,
      (__attribute__((address_space(3))) void*)s, 16, 0, 0);
}

// ---------------- X fp32 -> bf16, padded to 8320 rows (zeros) ----------------
__global__ __launch_bounds__(256) void conv_x(const float* __restrict__ X,
                                              ushort* __restrict__ Xb) {
  int t = blockIdx.x * 256 + threadIdx.x;
  if (t >= 8320 * 96) return;
  int row = t / 96;
  size_t e = (size_t)t * 8;
  union { uint4 q; ushort us[8]; } o;
  if (row < 8200) {
    float4 f0 = *(const float4*)(X + e);
    float4 f1 = *(const float4*)(X + e + 4);
    o.us[0] = f2bf(f0.x); o.us[1] = f2bf(f0.y); o.us[2] = f2bf(f0.z); o.us[3] = f2bf(f0.w);
    o.us[4] = f2bf(f1.x); o.us[5] = f2bf(f1.y); o.us[6] = f2bf(f1.z); o.us[7] = f2bf(f1.w);
  } else {
    o.q = make_uint4(0, 0, 0, 0);
  }
  *(uint4*)(Xb + e) = o.q;
}

// ---------------- W[q|k|v] fp32 -> Wt [N=2304][K=768] bf16 (+ bias fold) ----
__global__ __launch_bounds__(256) void pack_w(const float* __restrict__ Wq,
                                              const float* __restrict__ Wk,
                                              const float* __restrict__ Wv,
                                              ushort* __restrict__ Wt,
                                              const float* __restrict__ bq,
                                              const float* __restrict__ bk,
                                              const float* __restrict__ bv,
                                              float* __restrict__ bc) {
  if (blockIdx.y == 0 && blockIdx.x < 9) {       // folded bias concat
    int t2 = blockIdx.x * 256 + threadIdx.x;
    if (t2 < 768) bc[t2] = bq[t2];
    else if (t2 < 1536) bc[t2] = bk[t2 - 768];
    else if (t2 < 2304) bc[t2] = bv[t2 - 1536];
  }
  __shared__ float tile[32][33];
  const int nt = blockIdx.x;
  const int kt = blockIdx.y;
  const int sel = nt / 24;
  const int o0 = (nt - sel * 24) * 32;
  const int k0 = kt * 32;
  const float* W = sel == 0 ? Wq : sel == 1 ? Wk : Wv;
  const int t = threadIdx.x;
  const int x = t & 31, y = t >> 5;
  for (int p = 0; p < 4; ++p)
    tile[y + p * 8][x] = W[(size_t)(k0 + y + p * 8) * 768 + o0 + x];
  __syncthreads();
  for (int p = 0; p < 4; ++p) {
    const int nl = y + p * 8;
    Wt[(size_t)(nt * 32 + nl) * 768 + k0 + x] = f2bf(tile[x][nl]);
  }
}

// ---------------- rel_bias repack v2: [H][S][S] -> MFMA C-frag order --------
// biasF[h][kt=17][w16=72][lane=64][e=16], e=ct*4+r2, pre-scaled by log2(e),
// cols>1024 pre-masked. Split by kt-half: LDS 16x580 f32 = 37 KB -> 4 blk/CU;
// stores vectorized to one dwordx4 per (lane,ct,kt), wave-coalesced.
__global__ __launch_bounds__(256, 4) void repack_bias_frag(
    const float* __restrict__ rel, float* __restrict__ bf) {
  __shared__ float lds[16][580];                // 580: +4-dword/row bank skew
  const int id = blockIdx.x;                    // 12*72*2
  const int half = id & 1;
  const int hw = id >> 1;
  const int h = hw / 72, w = hw - h * 72;
  const int t = threadIdx.x;
  const int W = half ? 512 : 576;               // kt 9..16 : kt 0..8
  const int cbase = half * 576;
  const float* src = rel + (size_t)h * SEQ * SEQ;
  for (int r = 0; r < 16; ++r) {
    int q = w * 16 + r; if (q > 1024) q = 1024;
    const float* row = src + (size_t)q * SEQ;
    for (int c = t; c < W; c += 256) {
      int col = cbase + c;
      lds[r][c] = (col <= 1024) ? row[col] * 1.44269504f : -3.0e30f;
    }
  }
  __syncthreads();
  const int lane = t >> 2, ct = t & 3;
  const int l16 = lane & 15, quad = lane >> 4;
  const int nkt = half ? 8 : 9;
  for (int ktl = 0; ktl < nkt; ++ktl) {
    const int kt = half * 9 + ktl;
    const int col = ktl * 64 + ct * 16 + l16;
    f32x4 v;
    v[0] = lds[quad * 4 + 0][col];
    v[1] = lds[quad * 4 + 1][col];
    v[2] = lds[quad * 4 + 2][col];
    v[3] = lds[quad * 4 + 3][col];
    *(f32x4*)(bf + (((size_t)h * 17 + kt) * 72 + w) * 1024 + lane * 16 + ct * 4) = v;
  }
}

// ---------------- fused QKV GEMM: [8320x768]*[768x2304] -> Q/K/V [B,H,S,64] --
// Epilogue v2: C staged through LDS (bf16, bias added), stored as coalesced
// dwordx4 into the per-head streams (consecutive seq rows are contiguous).
__global__ __launch_bounds__(256) void gemm_qkv(const ushort* __restrict__ A,
                                                const ushort* __restrict__ Bt,
                                                const float* __restrict__ bias,
                                                ushort* __restrict__ Qo,
                                                ushort* __restrict__ Ko,
                                                ushort* __restrict__ Vo) {
  __shared__ ushort a_sm[128 * 32];
  __shared__ ushort b_sm[128 * 32];
  __shared__ ushort c_sm[64 * 136];             // epilogue staging (136: b128-aligned, bank-skewed)
  const int t = threadIdx.x;
  const int lane = t & 63, wave = t >> 6;
  const int quad = lane >> 4, l16 = lane & 15;
  const int wrow = wave >> 1, wcol = wave & 1;
  const int m0 = blockIdx.x * 128, n0 = blockIdx.y * 128;

  f32x4 acc[4][4] = {};

  const ushort* a_g = A + (size_t)m0 * 768;
  const ushort* b_g = Bt + (size_t)n0 * 768;

  for (int k0 = 0; k0 < 768; k0 += 32) {
    __syncthreads();
    for (int r = 0; r < 2; ++r) {
      int c = r * 256 + t;
      int row = c >> 2;
      int colb = (c & 3) * 16;
      async16((const char*)(a_g + (size_t)row * 768 + k0) + colb, (char*)a_sm + c * 16);
      async16((const char*)(b_g + (size_t)row * 768 + k0) + colb, (char*)b_sm + c * 16);
    }
    __syncthreads();
    bf16x8 af[4], bfr[4];
    for (int i = 0; i < 4; ++i) {
      af[i]  = *(const bf16x8*)(a_sm + (wrow * 64 + i * 16 + l16) * 32 + quad * 8);
      bfr[i] = *(const bf16x8*)(b_sm + (wcol * 64 + i * 16 + l16) * 32 + quad * 8);
    }
    for (int i = 0; i < 4; ++i)
      for (int j = 0; j < 4; ++j)
        acc[i][j] = __builtin_amdgcn_mfma_f32_16x16x32_bf16(af[i], bfr[j], acc[i][j], 0, 0, 0);
  }

  // ---- epilogue: n-tile (128) lies in one of Q/K/V and spans 2 heads ----
  const int sel = n0 / 768;
  const int o0 = n0 - sel * 768;
  const int hh0 = o0 >> 6;
  ushort* dst = sel == 0 ? Qo : sel == 1 ? Ko : Vo;
  float bvj[4];
  for (int j = 0; j < 4; ++j) bvj[j] = bias[n0 + wcol * 64 + j * 16 + l16];

  for (int p = 0; p < 2; ++p) {
    __syncthreads();
    if (wrow == p) {
      for (int i = 0; i < 4; ++i)
        for (int j = 0; j < 4; ++j)
          for (int r = 0; r < 4; ++r)
            c_sm[(i * 16 + quad * 4 + r) * 136 + wcol * 64 + j * 16 + l16] =
                f2bf(acc[i][j][r] + bvj[j]);
    }
    __syncthreads();
    const int head = t >> 7;                    // 0 or 1
    const int ci = t & 127;
    for (int k = 0; k < 4; ++k) {
      int ch = ci + 128 * k;                    // 0..511 chunks of 16 B
      int row = ch >> 3, off = (ch & 7) * 8;
      int gm = m0 + p * 64 + row;
      if (gm < 8200) {
        int bb = gm / 1025, ss = gm - bb * 1025;
        uint4 v = *(const uint4*)(c_sm + row * 136 + head * 64 + off);
        *(uint4*)(dst + (((size_t)(bb * NH + hh0 + head) * SEQ + ss) << 6) + off) = v;
      }
    }
  }
}

// ---------------- flash attention v5 (unchanged) ----------------------------
__global__ __launch_bounds__(256, 4) void attn(const ushort* __restrict__ Qb,
                                               const ushort* __restrict__ Kb,
                                               const ushort* __restrict__ Vb,
                                               const float* __restrict__ biasF,
                                               float* __restrict__ out) {
  __shared__ char smem[36864];
  ushort* p_sm = (ushort*)smem;                 // 4 x [32][72]
  ushort* k_sm = (ushort*)(smem + 18432);       // [64][72]
  ushort* v_sm = (ushort*)(smem + 27648);       // [64][72] transposed [hd][k]

  const int t = threadIdx.x;
  const int lane = t & 63, wave = t >> 6;
  const int quad = lane >> 4, l16 = lane & 15;

  const int id = blockIdx.x;                    // [0,864)
  const int x = id & 7, s = id >> 3;            // s in [0,108)
  const int Gg = s / 9, qt = s - Gg * 9;
  const int G = Gg * 8 + x;                     // [0,96)
  const int b = G / 12, h = G - b * 12;
  const int q0 = qt * 128;

  const size_t bh = (size_t)(b * NH + h) * SEQ * 64;
  const ushort* Qp = Qb + bh;
  const ushort* Kp = Kb + bh;
  const ushort* Vp = Vb + bh;

  uint4 kpre0, kpre1, vpre0, vpre1;
  const int vkp2 = t & 31, vhb = (t >> 5) * 8;

  auto issue_kv = [&](int kb) {
    {
      int c = t, row = c >> 3, cb = (c & 7) * 8;
      int rk = kb + row; if (rk > 1024) rk = 1024;
      kpre0 = *(const uint4*)(Kp + (size_t)rk * 64 + cb);
    }
    {
      int c = t + 256, row = c >> 3, cb = (c & 7) * 8;
      int rk = kb + row; if (rk > 1024) rk = 1024;
      kpre1 = *(const uint4*)(Kp + (size_t)rk * 64 + cb);
    }
    {
      int r0 = kb + vkp2 * 2;
      int r0c = r0 > 1024 ? 1024 : r0;
      int r1c = r0 + 1 > 1024 ? 1024 : r0 + 1;
      vpre0 = *(const uint4*)(Vp + (size_t)r0c * 64 + vhb);
      vpre1 = *(const uint4*)(Vp + (size_t)r1c * 64 + vhb);
    }
  };

  issue_kv(0);

  ushort* pw = p_sm + wave * (32 * 72);
  const int qbase = q0 + wave * 32;
  for (int i = 0; i < 4; ++i) {
    int c = lane + 64 * i;
    int row = c >> 3, cb = (c & 7) * 8;
    int rq = qbase + row; if (rq > 1024) rq = 1024;
    *(uint4*)(pw + row * 72 + cb) = *(const uint4*)(Qp + (size_t)rq * 64 + cb);
  }
  bf16x8 qf[2][2];
  for (int rt = 0; rt < 2; ++rt)
    for (int ks = 0; ks < 2; ++ks)
      qf[rt][ks] = *(const bf16x8*)(pw + (rt * 16 + l16) * 72 + ks * 32 + quad * 8);

  float lst[8] = {0, 0, 0, 0, 0, 0, 0, 0};
  f32x4 oacc[2][4] = {};
  const float c_scale = 0.18033688f;            // (1/8) * log2(e)
  const float* bf_base = biasF +
      ((size_t)h * 17 * 72 + (qt * 8 + wave * 2)) * 1024 + (lane << 4);

  for (int kt = 0; kt < 17; ++kt) {
    __syncthreads();
    {
      int c = t;
      *(uint4*)(k_sm + (c >> 3) * 72 + (c & 7) * 8) = kpre0;
      c = t + 256;
      *(uint4*)(k_sm + (c >> 3) * 72 + (c & 7) * 8) = kpre1;
    }
    {
      union { uint4 q; ushort us[8]; } e0, e1;
      e0.q = vpre0; e1.q = vpre1;
      for (int e = 0; e < 8; ++e)
        *(unsigned*)(v_sm + (vhb + e) * 72 + vkp2 * 2) =
            (unsigned)e0.us[e] | ((unsigned)e1.us[e] << 16);
    }
    __syncthreads();

    const float* bfp = bf_base + (size_t)kt * (72 * 1024);
    f32x4 br[2][4];
    for (int rt = 0; rt < 2; ++rt)
      for (int ct = 0; ct < 4; ++ct)
        br[rt][ct] = *(const f32x4*)(bfp + rt * 1024 + ct * 4);

    if (kt < 16) issue_kv(kt * 64 + 64);

    f32x4 sc[2][4] = {};
    for (int ct = 0; ct < 4; ++ct)
      for (int ks = 0; ks < 2; ++ks) {
        bf16x8 kf = *(const bf16x8*)(k_sm + (ct * 16 + l16) * 72 + ks * 32 + quad * 8);
        sc[0][ct] = __builtin_amdgcn_mfma_f32_16x16x32_bf16(qf[0][ks], kf, sc[0][ct], 0, 0, 0);
        sc[1][ct] = __builtin_amdgcn_mfma_f32_16x16x32_bf16(qf[1][ks], kf, sc[1][ct], 0, 0, 0);
      }

    for (int rt = 0; rt < 2; ++rt)
      for (int ct = 0; ct < 4; ++ct)
        for (int r2 = 0; r2 < 4; ++r2) {
          float p = __builtin_amdgcn_exp2f(
              fmaf(sc[rt][ct][r2], c_scale, br[rt][ct][r2]));
          lst[rt * 4 + r2] += p;
          pw[(rt * 16 + quad * 4 + r2) * 72 + ct * 16 + l16] = f2bf_p(p);
        }

    for (int ks = 0; ks < 2; ++ks) {
      bf16x8 pf0 = *(const bf16x8*)(pw + l16 * 72 + ks * 32 + quad * 8);
      bf16x8 pf1 = *(const bf16x8*)(pw + (16 + l16) * 72 + ks * 32 + quad * 8);
      for (int c4 = 0; c4 < 4; ++c4) {
        bf16x8 vf = *(const bf16x8*)(v_sm + (c4 * 16 + l16) * 72 + ks * 32 + quad * 8);
        oacc[0][c4] = __builtin_amdgcn_mfma_f32_16x16x32_bf16(pf0, vf, oacc[0][c4], 0, 0, 0);
        oacc[1][c4] = __builtin_amdgcn_mfma_f32_16x16x32_bf16(pf1, vf, oacc[1][c4], 0, 0, 0);
      }
    }
  }

  for (int si = 0; si < 8; ++si) {
    float s2 = lst[si];
    s2 += __shfl_xor(s2, 1);
    s2 += __shfl_xor(s2, 2);
    s2 += __shfl_xor(s2, 4);
    s2 += __shfl_xor(s2, 8);
    lst[si] = s2;
  }
  for (int rt = 0; rt < 2; ++rt)
    for (int r2 = 0; r2 < 4; ++r2) {
      int sr = qbase + rt * 16 + quad * 4 + r2;
      if (sr < SEQ) {
        float inv = 1.0f / lst[rt * 4 + r2];
        float* op = out + ((size_t)b * SEQ + sr) * 768 + h * 64;
        for (int c4 = 0; c4 < 4; ++c4)
          op[c4 * 16 + l16] = oacc[rt][c4][r2] * inv;
      }
    }
}

// ---------------- launch ----------------
extern "C" void kernel_launch(void* const* d_in, const int* in_sizes, int n_in,
                              void* d_out, int out_size, void* d_ws, size_t ws_size,
                              hipStream_t stream) {
  const float* X  = (const float*)d_in[0];
  const float* rb = (const float*)d_in[1];
  const float* Wq = (const float*)d_in[2];
  const float* bq = (const float*)d_in[3];
  const float* Wk = (const float*)d_in[4];
  const float* bk = (const float*)d_in[5];
  const float* Wv = (const float*)d_in[6];
  const float* bv = (const float*)d_in[7];
  float* out = (float*)d_out;
  char* ws = (char*)d_ws;

  // layout (biasF overlays Xb/Wt/biasc, which are dead after gemm_qkv):
  ushort* Qb    = (ushort*)ws;                          // 12,595,200 B
  ushort* Kb    = (ushort*)(ws + 12595200);
  ushort* Vb    = (ushort*)(ws + 25190400);             // ends 37,785,600
  ushort* Xb    = (ushort*)(ws + 37785600);             // 12,779,520 -> 50,565,120
  ushort* Wt    = (ushort*)(ws + 50565120);             //  3,538,944 -> 54,104,064
  float*  biasc = (float*)(ws + 54104064);              //      9,216 -> 54,113,280
  float*  biasF = (float*)(ws + 37785600);              // 60,162,048 -> 97,947,648

  conv_x<<<3120, 256, 0, stream>>>(X, Xb);
  pack_w<<<dim3(72, 24), 256, 0, stream>>>(Wq, Wk, Wv, Wt, bq, bk, bv, biasc);
  gemm_qkv<<<dim3(65, 18), 256, 0, stream>>>(Xb, Wt, biasc, Qb, Kb, Vb);
  repack_bias_frag<<<NH * 72 * 2, 256, 0, stream>>>(rb, biasF);
  attn<<<864, 256, 0, stream>>>(Qb, Kb, Vb, biasF, out);
}